// Round 9
// baseline (456.903 us; speedup 1.0000x reference)
//
#include <hip/hip_runtime.h>

// ---------------------------------------------------------------------------
// GIN inference, round 8:
//  - degree sort REVERTED (R5 406 vs R7 432: perm scatters agg writes, net loss)
//  - aggregation FUSED into the MLP kernel (agg -> LDS -> W1 -> LDS -> W2):
//    saves 25.6 MB/layer sum round-trip + 1 launch/layer
//  - bucket_scatter: bucket id stored at placement (no binary search in flush)
// ---------------------------------------------------------------------------

typedef __attribute__((ext_vector_type(8))) short short8;   // 8 bf16 (4 VGPRs)
typedef __attribute__((ext_vector_type(4))) float floatx4;  // 4 fp32 acc

__device__ __forceinline__ unsigned f2bf(float f) {
    unsigned u = __float_as_uint(f);
    return (u + 0x7fffu + ((u >> 16) & 1u)) >> 16;   // RNE
}
__device__ __forceinline__ float bf2f(unsigned short b) {
    return __uint_as_float(((unsigned)b) << 16);
}
__device__ __forceinline__ float bflo(unsigned u) { return __uint_as_float(u << 16); }
__device__ __forceinline__ float bfhi(unsigned u) { return __uint_as_float(u & 0xffff0000u); }

__device__ __forceinline__ uint4 pack8bf(const float* v) {
    uint4 o;
    o.x = f2bf(v[0]) | (f2bf(v[1]) << 16);
    o.y = f2bf(v[2]) | (f2bf(v[3]) << 16);
    o.z = f2bf(v[4]) | (f2bf(v[5]) << 16);
    o.w = f2bf(v[6]) | (f2bf(v[7]) << 16);
    return o;
}

// ======================= bucketed CSR build =======================

__global__ void bucket_hist(const int* __restrict__ dstA, int* __restrict__ bcnt,
                            int E, int nb) {
    __shared__ int hist[512];
    int tid = threadIdx.x;
    int start = blockIdx.x * 4096;
    for (int i = tid; i < 512; i += 256) hist[i] = 0;
    __syncthreads();
#pragma unroll
    for (int t = 0; t < 16; ++t) {
        int e = start + t * 256 + tid;
        if (e < E) atomicAdd(&hist[dstA[e] >> 7], 1);
    }
    __syncthreads();
    for (int i = tid; i < nb; i += 256)
        if (hist[i]) atomicAdd(&bcnt[i], hist[i]);
}

__global__ void scan_buckets(const int* __restrict__ bcnt, int* __restrict__ boff,
                             int* __restrict__ bcur, int* __restrict__ rowptr,
                             int nb, int N) {
    __shared__ int sa[512], sb[512];
    int t = threadIdx.x;
    sa[t] = (t < nb) ? bcnt[t] : 0;
    __syncthreads();
    int* ps = sa;
    int* pd = sb;
    for (int o = 1; o < 512; o <<= 1) {
        pd[t] = ps[t] + ((t >= o) ? ps[t - o] : 0);
        __syncthreads();
        int* tmp = ps; ps = pd; pd = tmp;
    }
    if (t <= nb) boff[t] = (t == 0) ? 0 : ps[t - 1];
    if (t < nb) bcur[t] = (t == 0) ? 0 : ps[t - 1];
    if (t == 0) rowptr[N] = ps[nb - 1];
}

__global__ void bucket_scatter(const int* __restrict__ srcA, const int* __restrict__ dstA,
                               int* __restrict__ bcur, unsigned* __restrict__ staging,
                               int E, int nb) {
    __shared__ int hist[512];
    __shared__ int sa[512], sb[512];
    __shared__ int toff[513];
    __shared__ int gbase[512];
    __shared__ unsigned pk[4096];
    __shared__ unsigned short bkt[4096];
    int tid = threadIdx.x;
    int start = blockIdx.x * 4096;
    for (int i = tid; i < 512; i += 256) hist[i] = 0;
    __syncthreads();
    int bidx[16], rank[16];
    unsigned pval[16];
#pragma unroll
    for (int t = 0; t < 16; ++t) {
        int e = start + t * 256 + tid;
        bidx[t] = -1;
        if (e < E) {
            int d = dstA[e];
            int s = srcA[e];
            int b = d >> 7;
            bidx[t] = b;
            rank[t] = atomicAdd(&hist[b], 1);
            pval[t] = ((unsigned)s << 7) | (unsigned)(d & 127);
        }
    }
    __syncthreads();
    sa[tid] = hist[tid];
    sa[tid + 256] = hist[tid + 256];
    __syncthreads();
    int* ps = sa;
    int* pd = sb;
    for (int o = 1; o < 512; o <<= 1) {
        pd[tid] = ps[tid] + ((tid >= o) ? ps[tid - o] : 0);
        int j2 = tid + 256;
        pd[j2] = ps[j2] + ((j2 >= o) ? ps[j2 - o] : 0);
        __syncthreads();
        int* tmp = ps; ps = pd; pd = tmp;
    }
    toff[tid + 1] = ps[tid];
    toff[tid + 257] = ps[tid + 256];
    if (tid == 0) toff[0] = 0;
    __syncthreads();
    for (int b = tid; b < nb; b += 256) {
        int c = hist[b];
        gbase[b] = c ? atomicAdd(&bcur[b], c) : 0;
    }
#pragma unroll
    for (int t = 0; t < 16; ++t)
        if (bidx[t] >= 0) {
            int pos = toff[bidx[t]] + rank[t];
            pk[pos] = pval[t];
            bkt[pos] = (unsigned short)bidx[t];
        }
    __syncthreads();
    int total = toff[512];
    for (int i = tid; i < total; i += 256) {
        int b = bkt[i];
        staging[gbase[b] + (i - toff[b])] = pk[i];
    }
}

__global__ void bucket_build(const unsigned* __restrict__ staging, const int* __restrict__ boff,
                             int* __restrict__ rowptr, int* __restrict__ col, int N) {
    __shared__ int deg[128], sca[128], scb[128], curL[128];
    __shared__ unsigned pk[4096];
    __shared__ int colL[4096];
    int b = blockIdx.x, tid = threadIdx.x;
    int lo = boff[b], hi = boff[b + 1];
    int cnt = hi - lo;
    if (cnt > 4096) cnt = 4096;
    for (int i = tid; i < cnt; i += 256) pk[i] = staging[lo + i];
    if (tid < 128) deg[tid] = 0;
    __syncthreads();
    for (int i = tid; i < cnt; i += 256) atomicAdd(&deg[pk[i] & 127u], 1);
    __syncthreads();
    if (tid < 128) sca[tid] = deg[tid];
    __syncthreads();
    int* ps = sca;
    int* pd = scb;
    for (int o = 1; o < 128; o <<= 1) {
        if (tid < 128) pd[tid] = ps[tid] + ((tid >= o) ? ps[tid - o] : 0);
        __syncthreads();
        int* tmp = ps; ps = pd; pd = tmp;
    }
    if (tid < 128) {
        int excl = tid ? ps[tid - 1] : 0;
        curL[tid] = excl;
        int node = b * 128 + tid;
        if (node < N) rowptr[node] = lo + excl;
    }
    __syncthreads();
    for (int i = tid; i < cnt; i += 256) {
        unsigned v = pk[i];
        int p = atomicAdd(&curL[v & 127u], 1);
        colL[p] = (int)(v >> 7);
    }
    __syncthreads();
    for (int i = tid; i < cnt; i += 256) col[lo + i] = colL[i];
}

// ======================= weight packing (perm-aware) =======================

__global__ void pack_W_all(const float* __restrict__ c1W2, const float* __restrict__ csW1,
                           const float* __restrict__ csW2, unsigned short* __restrict__ Wp,
                           int NL) {
    int slot = blockIdx.x >> 6;
    int r = (blockIdx.x & 63) * 256 + threadIdx.x;   // 0..16383
    const float* W = (slot == 0) ? c1W2
                   : (slot <= NL ? csW1 + (size_t)(slot - 1) * 16384
                                 : csW2 + (size_t)(slot - 1 - NL) * 16384);
    int j = r & 7, lane = (r >> 3) & 63, nt = (r >> 9) & 7, ks = (r >> 12) & 3;
    int u = ks * 32 + (lane >> 4) * 8 + j;
    int k = (u & 7) * 16 + (u >> 3);                 // pi(u)
    int n = nt * 16 + (lane & 15);
    Wp[(size_t)slot * 16384 + r] = (unsigned short)f2bf(W[k * 128 + n]);
}

// ======================= layer 1 (input dim = 2) =======================

__global__ void agg2(const float* __restrict__ x, const int* __restrict__ rowptr,
                     const int* __restrict__ col, float* __restrict__ sum2, int N) {
    int n = blockIdx.x * 256 + threadIdx.x;
    if (n >= N) return;
    const float2* x2 = (const float2*)x;
    float2 self = x2[n];
    float ax = self.x, ay = self.y;
    int e0 = rowptr[n], e1 = rowptr[n + 1];
    for (int j = e0; j < e1; ++j) {
        float2 v = x2[col[j]];
        ax += v.x;
        ay += v.y;
    }
    sum2[2 * n] = ax;
    sum2[2 * n + 1] = ay;
}

__global__ void mlp1a(const float* __restrict__ sum2, const float* __restrict__ W1,
                      const float* __restrict__ b1, unsigned short* __restrict__ out, int N) {
    int idx = blockIdx.x * 256 + threadIdx.x;
    if (idx >= N * 128) return;
    int n = idx >> 7, p = idx & 127;
    int c = (p & 7) * 16 + (p >> 3);
    float v = fmaf(sum2[2 * n], W1[c], fmaf(sum2[2 * n + 1], W1[128 + c], b1[c]));
    out[idx] = (unsigned short)f2bf(fmaxf(v, 0.f));
}

// ======================= fused agg + GIN MLP ================================
// 64 nodes/block, 256 threads (4 waves).
// Stage A: gather-aggregate rows into aggL (4 passes x 16 nodes; subgroup of
//   16 lanes x uint4 per row, 8x unrolled) -- identical numerics to aggH.
// barrier. Stage B: wave w runs the 2-stage MFMA MLP on LDS rows w*16..w*16+15
//   (wave-private after the barrier; MLP mid-buffer overwrites aggL in place).

__launch_bounds__(256)
__global__ void agg_mlp(const uint4* __restrict__ h4,
                        const int* __restrict__ rowptr, const int* __restrict__ col,
                        const unsigned short* __restrict__ W1p, const float* __restrict__ b1,
                        const unsigned short* __restrict__ W2p, const float* __restrict__ b2,
                        const float* __restrict__ gamma, const float* __restrict__ beta,
                        const float* __restrict__ mean, const float* __restrict__ var,
                        unsigned short* __restrict__ out, int N) {
    __shared__ unsigned short aggL[64][136];   // 272B stride: 2-way bank alias (free)
    int wave = threadIdx.x >> 6, lane = threadIdx.x & 63;
    int sub = lane >> 4, sl = lane & 15;
    int n0 = blockIdx.x * 64;

    // ---- stage A: aggregate 64 rows into LDS ----
#pragma unroll
    for (int pass = 0; pass < 4; ++pass) {
        int li = pass * 16 + wave * 4 + sub;       // local row 0..63
        int n = n0 + li;
        float acc[8] = {0.f, 0.f, 0.f, 0.f, 0.f, 0.f, 0.f, 0.f};
        if (n < N) {
            size_t base = (size_t)n * 16 + sl;
            uint4 self = h4[base];
            acc[0] = bflo(self.x); acc[1] = bfhi(self.x);
            acc[2] = bflo(self.y); acc[3] = bfhi(self.y);
            acc[4] = bflo(self.z); acc[5] = bfhi(self.z);
            acc[6] = bflo(self.w); acc[7] = bfhi(self.w);
            int e0 = rowptr[n], e1 = rowptr[n + 1];
            int j = e0;
            for (; j + 8 <= e1; j += 8) {
                int s[8];
#pragma unroll
                for (int t = 0; t < 8; ++t) s[t] = col[j + t];
                uint4 v[8];
#pragma unroll
                for (int t = 0; t < 8; ++t) v[t] = h4[(size_t)s[t] * 16 + sl];
#pragma unroll
                for (int t = 0; t < 8; ++t) {
                    acc[0] += bflo(v[t].x); acc[1] += bfhi(v[t].x);
                    acc[2] += bflo(v[t].y); acc[3] += bfhi(v[t].y);
                    acc[4] += bflo(v[t].z); acc[5] += bfhi(v[t].z);
                    acc[6] += bflo(v[t].w); acc[7] += bfhi(v[t].w);
                }
            }
            for (; j < e1; ++j) {
                uint4 v = h4[(size_t)col[j] * 16 + sl];
                acc[0] += bflo(v.x); acc[1] += bfhi(v.x);
                acc[2] += bflo(v.y); acc[3] += bfhi(v.y);
                acc[4] += bflo(v.z); acc[5] += bfhi(v.z);
                acc[6] += bflo(v.w); acc[7] += bfhi(v.w);
            }
        }
        *(uint4*)&aggL[li][sl * 8] = pack8bf(acc);
    }
    __syncthreads();

    // ---- stage B: MLP on wave-private rows ----
    int m = lane & 15, q = lane >> 4;
    int lr = wave * 16 + m;                        // local row for A-frag

    short8 a[4];
#pragma unroll
    for (int ks = 0; ks < 4; ++ks)
        a[ks] = *(const short8*)&aggL[lr][ks * 32 + q * 8];

    floatx4 c[8];
#pragma unroll
    for (int nt = 0; nt < 8; ++nt) c[nt] = (floatx4){0.f, 0.f, 0.f, 0.f};
#pragma unroll
    for (int nt = 0; nt < 8; ++nt) {
        short8 w0 = *(const short8*)&W1p[((0 * 8 + nt) * 64 + lane) * 8];
        short8 w1 = *(const short8*)&W1p[((1 * 8 + nt) * 64 + lane) * 8];
        short8 w2 = *(const short8*)&W1p[((2 * 8 + nt) * 64 + lane) * 8];
        short8 w3 = *(const short8*)&W1p[((3 * 8 + nt) * 64 + lane) * 8];
        c[nt] = __builtin_amdgcn_mfma_f32_16x16x32_bf16(a[0], w0, c[nt], 0, 0, 0);
        c[nt] = __builtin_amdgcn_mfma_f32_16x16x32_bf16(a[1], w1, c[nt], 0, 0, 0);
        c[nt] = __builtin_amdgcn_mfma_f32_16x16x32_bf16(a[2], w2, c[nt], 0, 0, 0);
        c[nt] = __builtin_amdgcn_mfma_f32_16x16x32_bf16(a[3], w3, c[nt], 0, 0, 0);
    }

    // stage-1 epilogue -> same LDS rows (wave-private; A-frags already in regs)
    float b1v[8];
#pragma unroll
    for (int nt = 0; nt < 8; ++nt) b1v[nt] = b1[nt * 16 + m];
#pragma unroll
    for (int rg = 0; rg < 4; ++rg) {
        float v[8];
#pragma unroll
        for (int nt = 0; nt < 8; ++nt) v[nt] = fmaxf(c[nt][rg] + b1v[nt], 0.f);
        *(uint4*)&aggL[wave * 16 + q * 4 + rg][m * 8] = pack8bf(v);
    }

    short8 d[4];
#pragma unroll
    for (int ks = 0; ks < 4; ++ks)
        d[ks] = *(const short8*)&aggL[lr][ks * 32 + q * 8];

    floatx4 e[8];
#pragma unroll
    for (int nt = 0; nt < 8; ++nt) e[nt] = (floatx4){0.f, 0.f, 0.f, 0.f};
#pragma unroll
    for (int nt = 0; nt < 8; ++nt) {
        short8 w0 = *(const short8*)&W2p[((0 * 8 + nt) * 64 + lane) * 8];
        short8 w1 = *(const short8*)&W2p[((1 * 8 + nt) * 64 + lane) * 8];
        short8 w2 = *(const short8*)&W2p[((2 * 8 + nt) * 64 + lane) * 8];
        short8 w3 = *(const short8*)&W2p[((3 * 8 + nt) * 64 + lane) * 8];
        e[nt] = __builtin_amdgcn_mfma_f32_16x16x32_bf16(d[0], w0, e[nt], 0, 0, 0);
        e[nt] = __builtin_amdgcn_mfma_f32_16x16x32_bf16(d[1], w1, e[nt], 0, 0, 0);
        e[nt] = __builtin_amdgcn_mfma_f32_16x16x32_bf16(d[2], w2, e[nt], 0, 0, 0);
        e[nt] = __builtin_amdgcn_mfma_f32_16x16x32_bf16(d[3], w3, e[nt], 0, 0, 0);
    }

    float b2v[8], scl[8], shf[8];
#pragma unroll
    for (int nt = 0; nt < 8; ++nt) {
        int cc = nt * 16 + m;
        b2v[nt] = b2[cc];
        float s = gamma[cc] * rsqrtf(var[cc] + 1e-5f);
        scl[nt] = s;
        shf[nt] = beta[cc] - mean[cc] * s;
    }
#pragma unroll
    for (int rg = 0; rg < 4; ++rg) {
        int r0 = n0 + wave * 16 + q * 4 + rg;
        float v[8];
#pragma unroll
        for (int nt = 0; nt < 8; ++nt)
            v[nt] = fmaf(fmaxf(e[nt][rg] + b2v[nt], 0.f), scl[nt], shf[nt]);
        if (r0 < N) *(uint4*)&out[(size_t)r0 * 128 + m * 8] = pack8bf(v);
    }
}

// ======================= layer-1 single GEMM (64 rows/block) ================

__launch_bounds__(128)
__global__ void gemm_one(const unsigned short* __restrict__ A,
                         const unsigned short* __restrict__ Wp,
                         const float* __restrict__ bias,
                         const float* __restrict__ gamma, const float* __restrict__ beta,
                         const float* __restrict__ mean, const float* __restrict__ var,
                         unsigned short* __restrict__ out, int N) {
    int wave = threadIdx.x >> 6, lane = threadIdx.x & 63;
    int row0 = blockIdx.x * 64 + wave * 32;
    if (row0 >= N) return;
    int m = lane & 15, q = lane >> 4;
    int ra = row0 + m;      if (ra > N - 1) ra = N - 1;
    int rb = row0 + 16 + m; if (rb > N - 1) rb = N - 1;

    short8 a0[4], a1[4];
#pragma unroll
    for (int ks = 0; ks < 4; ++ks) {
        a0[ks] = *(const short8*)&A[(size_t)ra * 128 + ks * 32 + q * 8];
        a1[ks] = *(const short8*)&A[(size_t)rb * 128 + ks * 32 + q * 8];
    }
    floatx4 c0[8], c1[8];
#pragma unroll
    for (int nt = 0; nt < 8; ++nt) {
        c0[nt] = (floatx4){0.f, 0.f, 0.f, 0.f};
        c1[nt] = (floatx4){0.f, 0.f, 0.f, 0.f};
    }
#pragma unroll
    for (int nt = 0; nt < 8; ++nt) {
        short8 w0 = *(const short8*)&Wp[((0 * 8 + nt) * 64 + lane) * 8];
        short8 w1 = *(const short8*)&Wp[((1 * 8 + nt) * 64 + lane) * 8];
        short8 w2 = *(const short8*)&Wp[((2 * 8 + nt) * 64 + lane) * 8];
        short8 w3 = *(const short8*)&Wp[((3 * 8 + nt) * 64 + lane) * 8];
        c0[nt] = __builtin_amdgcn_mfma_f32_16x16x32_bf16(a0[0], w0, c0[nt], 0, 0, 0);
        c1[nt] = __builtin_amdgcn_mfma_f32_16x16x32_bf16(a1[0], w0, c1[nt], 0, 0, 0);
        c0[nt] = __builtin_amdgcn_mfma_f32_16x16x32_bf16(a0[1], w1, c0[nt], 0, 0, 0);
        c1[nt] = __builtin_amdgcn_mfma_f32_16x16x32_bf16(a1[1], w1, c1[nt], 0, 0, 0);
        c0[nt] = __builtin_amdgcn_mfma_f32_16x16x32_bf16(a0[2], w2, c0[nt], 0, 0, 0);
        c1[nt] = __builtin_amdgcn_mfma_f32_16x16x32_bf16(a1[2], w2, c1[nt], 0, 0, 0);
        c0[nt] = __builtin_amdgcn_mfma_f32_16x16x32_bf16(a0[3], w3, c0[nt], 0, 0, 0);
        c1[nt] = __builtin_amdgcn_mfma_f32_16x16x32_bf16(a1[3], w3, c1[nt], 0, 0, 0);
    }
    float bv[8], scl[8], shf[8];
#pragma unroll
    for (int nt = 0; nt < 8; ++nt) {
        int cc = nt * 16 + m;
        bv[nt] = bias[cc];
        float s = gamma[cc] * rsqrtf(var[cc] + 1e-5f);
        scl[nt] = s;
        shf[nt] = beta[cc] - mean[cc] * s;
    }
#pragma unroll
    for (int rg = 0; rg < 4; ++rg) {
        int r0 = row0 + q * 4 + rg;
        int r1 = row0 + 16 + q * 4 + rg;
        float v0[8], v1[8];
#pragma unroll
        for (int nt = 0; nt < 8; ++nt) {
            v0[nt] = fmaf(fmaxf(c0[nt][rg] + bv[nt], 0.f), scl[nt], shf[nt]);
            v1[nt] = fmaf(fmaxf(c1[nt][rg] + bv[nt], 0.f), scl[nt], shf[nt]);
        }
        if (r0 < N) *(uint4*)&out[(size_t)r0 * 128 + m * 8] = pack8bf(v0);
        if (r1 < N) *(uint4*)&out[(size_t)r1 * 128 + m * 8] = pack8bf(v1);
    }
}

// ======================= pooling: parallel partial sums + head ==============

__global__ void pool_partial(const unsigned short* __restrict__ h,
                             const int* __restrict__ batch,
                             float* __restrict__ pooled, int N) {
    int c = threadIdx.x;              // 0..127
    int n0 = blockIdx.x * 32;
    int n1 = n0 + 32; if (n1 > N) n1 = N;
    if (n0 >= N) return;
    int cg = batch[n0];
    float acc = 0.f;
    for (int n = n0; n < n1; ++n) {
        int g = batch[n];
        if (g != cg) {
            atomicAdd(&pooled[(size_t)cg * 128 + c], acc);
            acc = 0.f;
            cg = g;
        }
        acc += bf2f(h[(size_t)n * 128 + c]);
    }
    atomicAdd(&pooled[(size_t)cg * 128 + c], acc);
}

__global__ void head(const float* __restrict__ pooled,
                     const float* __restrict__ lin1W, const float* __restrict__ lin1b,
                     const float* __restrict__ lin2W, const float* __restrict__ lin2b,
                     float* __restrict__ out) {
    int g = blockIdx.x;
    int c = threadIdx.x;  // 0..127
    __shared__ float pl[128];
    pl[c] = pooled[(size_t)g * 128 + c];
    __syncthreads();

    float o = lin1b[c];
    for (int k = 0; k < 128; ++k) {
        int ko = (k & 7) * 16 + (k >> 3);   // orig col held at permuted position k
        o = fmaf(pl[k], lin1W[ko * 128 + c], o);
    }
    o = fmaxf(o, 0.f) * lin2W[c];

    __shared__ float red[128];
    red[c] = o;
    __syncthreads();
    for (int off = 64; off > 0; off >>= 1) {
        if (c < off) red[c] += red[c + off];
        __syncthreads();
    }
    if (c == 0) out[g] = red[0] + lin2b[0];
}

// ---------------------------------------------------------------------------

extern "C" void kernel_launch(void* const* d_in, const int* in_sizes, int n_in,
                              void* d_out, int out_size, void* d_ws, size_t ws_size,
                              hipStream_t stream) {
    const float* x     = (const float*)d_in[0];
    const int*   ei    = (const int*)d_in[1];
    const int*   batch = (const int*)d_in[2];
    const float* c1W1  = (const float*)d_in[3];
    const float* c1b1  = (const float*)d_in[4];
    const float* c1W2  = (const float*)d_in[5];
    const float* c1b2  = (const float*)d_in[6];
    const float* c1g   = (const float*)d_in[7];
    const float* c1be  = (const float*)d_in[8];
    const float* c1m   = (const float*)d_in[9];
    const float* c1v   = (const float*)d_in[10];
    const float* csW1  = (const float*)d_in[11];
    const float* csb1  = (const float*)d_in[12];
    const float* csW2  = (const float*)d_in[13];
    const float* csb2  = (const float*)d_in[14];
    const float* csg   = (const float*)d_in[15];
    const float* csbe  = (const float*)d_in[16];
    const float* csm   = (const float*)d_in[17];
    const float* csv   = (const float*)d_in[18];
    const float* lin1W = (const float*)d_in[19];
    const float* lin1b = (const float*)d_in[20];
    const float* lin2W = (const float*)d_in[21];
    const float* lin2b = (const float*)d_in[22];

    const int N = in_sizes[0] / 2;
    const int E = in_sizes[1] / 2;
    const int G = out_size;
    const int NL = in_sizes[11] / (128 * 128);  // 4
    const int nb = (N + 127) >> 7;              // buckets of 128 nodes

    char* ws = (char*)d_ws;
    size_t HS = (size_t)N * 128 * sizeof(unsigned short);      // bf16 feature plane
    unsigned short* h   = (unsigned short*)(ws);
    unsigned short* tmp = (unsigned short*)(ws + HS);
    char* p = ws + 2 * HS;
    float* sum2 = (float*)p;                 p += (((size_t)N * 2 * 4 + 15) / 16) * 16;
    unsigned short* Wp = (unsigned short*)p; p += ((9 * 16384 * 2 + 15) / 16) * 16;
    int* rowptr = (int*)p;                   p += (((size_t)(N + 1) * 4 + 15) / 16) * 16;
    int* col = (int*)p;                      p += (((size_t)E * 4 + 15) / 16) * 16;
    unsigned* staging = (unsigned*)p;        p += (((size_t)E * 4 + 15) / 16) * 16;
    int* bcnt = (int*)p;                     p += 512 * 4;
    int* boff = (int*)p;                     p += 513 * 4;
    int* bcur = (int*)p;                     p += 512 * 4;
    float* pooled = (float*)p;               p += (size_t)G * 128 * 4;

    const int* srcI = ei;
    const int* dstI = ei + E;

    const int NB = (N + 255) / 256;
    const int ET = (E + 4095) / 4096;

    // CSR build (bucketed, no scattered global writes)
    (void)hipMemsetAsync(bcnt, 0, 512 * 4, stream);
    (void)hipMemsetAsync(pooled, 0, (size_t)G * 128 * 4, stream);
    bucket_hist<<<ET, 256, 0, stream>>>(dstI, bcnt, E, nb);
    scan_buckets<<<1, 512, 0, stream>>>(bcnt, boff, bcur, rowptr, nb, N);
    bucket_scatter<<<ET, 256, 0, stream>>>(srcI, dstI, bcur, staging, E, nb);
    bucket_build<<<nb, 256, 0, stream>>>(staging, boff, rowptr, col, N);

    // weight packing
    pack_W_all<<<(1 + 2 * NL) * 64, 256, 0, stream>>>(c1W2, csW1, csW2, Wp, NL);

    const int FB = (N + 63) / 64;

    // layer 1 (input dim 2)
    agg2<<<NB, 256, 0, stream>>>(x, rowptr, col, sum2, N);
    mlp1a<<<(N * 128 + 255) / 256, 256, 0, stream>>>(sum2, c1W1, c1b1, tmp, N);
    gemm_one<<<FB, 128, 0, stream>>>(tmp, Wp, c1b2, c1g, c1be, c1m, c1v, h, N);

    // layers 2..5: fused aggregation + MLP (ping-pong h <-> tmp)
    unsigned short* cur = h;
    unsigned short* nxt = tmp;
    for (int i = 0; i < NL; ++i) {
        agg_mlp<<<FB, 256, 0, stream>>>((const uint4*)cur, rowptr, col,
                                        Wp + (size_t)(1 + i) * 16384, csb1 + i * 128,
                                        Wp + (size_t)(1 + NL + i) * 16384, csb2 + i * 128,
                                        csg + i * 128, csbe + i * 128, csm + i * 128,
                                        csv + i * 128, nxt, N);
        unsigned short* t = cur; cur = nxt; nxt = t;
    }

    // pooling + head
    pool_partial<<<(N + 31) / 32, 128, 0, stream>>>(cur, batch, pooled, N);
    head<<<G, 128, 0, stream>>>(pooled, lin1W, lin1b, lin2W, lin2b, (float*)d_out);
}

// Round 10
// 426.353 us; speedup vs baseline: 1.0717x; 1.0717x over previous
//
#include <hip/hip_runtime.h>

// ---------------------------------------------------------------------------
// GIN inference, round 9:
//  - REVERT R8 fusion (agg_mlp occupancy 17.9% vs aggH 65%: gather is
//    TLP-bound; 3125 waves vs 12500 starved it). Back to R5 structure.
//  - aggH: gather unroll 8 -> 16 (more loads in flight per lane)
//  - keep R8's bucket_scatter (no binary search in flush)
// ---------------------------------------------------------------------------

typedef __attribute__((ext_vector_type(8))) short short8;   // 8 bf16 (4 VGPRs)
typedef __attribute__((ext_vector_type(4))) float floatx4;  // 4 fp32 acc

__device__ __forceinline__ unsigned f2bf(float f) {
    unsigned u = __float_as_uint(f);
    return (u + 0x7fffu + ((u >> 16) & 1u)) >> 16;   // RNE
}
__device__ __forceinline__ float bf2f(unsigned short b) {
    return __uint_as_float(((unsigned)b) << 16);
}
__device__ __forceinline__ float bflo(unsigned u) { return __uint_as_float(u << 16); }
__device__ __forceinline__ float bfhi(unsigned u) { return __uint_as_float(u & 0xffff0000u); }

__device__ __forceinline__ uint4 pack8bf(const float* v) {
    uint4 o;
    o.x = f2bf(v[0]) | (f2bf(v[1]) << 16);
    o.y = f2bf(v[2]) | (f2bf(v[3]) << 16);
    o.z = f2bf(v[4]) | (f2bf(v[5]) << 16);
    o.w = f2bf(v[6]) | (f2bf(v[7]) << 16);
    return o;
}

// ======================= bucketed CSR build =======================

__global__ void bucket_hist(const int* __restrict__ dstA, int* __restrict__ bcnt,
                            int E, int nb) {
    __shared__ int hist[512];
    int tid = threadIdx.x;
    int start = blockIdx.x * 4096;
    for (int i = tid; i < 512; i += 256) hist[i] = 0;
    __syncthreads();
#pragma unroll
    for (int t = 0; t < 16; ++t) {
        int e = start + t * 256 + tid;
        if (e < E) atomicAdd(&hist[dstA[e] >> 7], 1);
    }
    __syncthreads();
    for (int i = tid; i < nb; i += 256)
        if (hist[i]) atomicAdd(&bcnt[i], hist[i]);
}

__global__ void scan_buckets(const int* __restrict__ bcnt, int* __restrict__ boff,
                             int* __restrict__ bcur, int* __restrict__ rowptr,
                             int nb, int N) {
    __shared__ int sa[512], sb[512];
    int t = threadIdx.x;
    sa[t] = (t < nb) ? bcnt[t] : 0;
    __syncthreads();
    int* ps = sa;
    int* pd = sb;
    for (int o = 1; o < 512; o <<= 1) {
        pd[t] = ps[t] + ((t >= o) ? ps[t - o] : 0);
        __syncthreads();
        int* tmp = ps; ps = pd; pd = tmp;
    }
    if (t <= nb) boff[t] = (t == 0) ? 0 : ps[t - 1];
    if (t < nb) bcur[t] = (t == 0) ? 0 : ps[t - 1];
    if (t == 0) rowptr[N] = ps[nb - 1];
}

__global__ void bucket_scatter(const int* __restrict__ srcA, const int* __restrict__ dstA,
                               int* __restrict__ bcur, unsigned* __restrict__ staging,
                               int E, int nb) {
    __shared__ int hist[512];
    __shared__ int sa[512], sb[512];
    __shared__ int toff[513];
    __shared__ int gbase[512];
    __shared__ unsigned pk[4096];
    __shared__ unsigned short bkt[4096];
    int tid = threadIdx.x;
    int start = blockIdx.x * 4096;
    for (int i = tid; i < 512; i += 256) hist[i] = 0;
    __syncthreads();
    int bidx[16], rank[16];
    unsigned pval[16];
#pragma unroll
    for (int t = 0; t < 16; ++t) {
        int e = start + t * 256 + tid;
        bidx[t] = -1;
        if (e < E) {
            int d = dstA[e];
            int s = srcA[e];
            int b = d >> 7;
            bidx[t] = b;
            rank[t] = atomicAdd(&hist[b], 1);
            pval[t] = ((unsigned)s << 7) | (unsigned)(d & 127);
        }
    }
    __syncthreads();
    sa[tid] = hist[tid];
    sa[tid + 256] = hist[tid + 256];
    __syncthreads();
    int* ps = sa;
    int* pd = sb;
    for (int o = 1; o < 512; o <<= 1) {
        pd[tid] = ps[tid] + ((tid >= o) ? ps[tid - o] : 0);
        int j2 = tid + 256;
        pd[j2] = ps[j2] + ((j2 >= o) ? ps[j2 - o] : 0);
        __syncthreads();
        int* tmp = ps; ps = pd; pd = tmp;
    }
    toff[tid + 1] = ps[tid];
    toff[tid + 257] = ps[tid + 256];
    if (tid == 0) toff[0] = 0;
    __syncthreads();
    for (int b = tid; b < nb; b += 256) {
        int c = hist[b];
        gbase[b] = c ? atomicAdd(&bcur[b], c) : 0;
    }
#pragma unroll
    for (int t = 0; t < 16; ++t)
        if (bidx[t] >= 0) {
            int pos = toff[bidx[t]] + rank[t];
            pk[pos] = pval[t];
            bkt[pos] = (unsigned short)bidx[t];
        }
    __syncthreads();
    int total = toff[512];
    for (int i = tid; i < total; i += 256) {
        int b = bkt[i];
        staging[gbase[b] + (i - toff[b])] = pk[i];
    }
}

__global__ void bucket_build(const unsigned* __restrict__ staging, const int* __restrict__ boff,
                             int* __restrict__ rowptr, int* __restrict__ col, int N) {
    __shared__ int deg[128], sca[128], scb[128], curL[128];
    __shared__ unsigned pk[4096];
    __shared__ int colL[4096];
    int b = blockIdx.x, tid = threadIdx.x;
    int lo = boff[b], hi = boff[b + 1];
    int cnt = hi - lo;
    if (cnt > 4096) cnt = 4096;
    for (int i = tid; i < cnt; i += 256) pk[i] = staging[lo + i];
    if (tid < 128) deg[tid] = 0;
    __syncthreads();
    for (int i = tid; i < cnt; i += 256) atomicAdd(&deg[pk[i] & 127u], 1);
    __syncthreads();
    if (tid < 128) sca[tid] = deg[tid];
    __syncthreads();
    int* ps = sca;
    int* pd = scb;
    for (int o = 1; o < 128; o <<= 1) {
        if (tid < 128) pd[tid] = ps[tid] + ((tid >= o) ? ps[tid - o] : 0);
        __syncthreads();
        int* tmp = ps; ps = pd; pd = tmp;
    }
    if (tid < 128) {
        int excl = tid ? ps[tid - 1] : 0;
        curL[tid] = excl;
        int node = b * 128 + tid;
        if (node < N) rowptr[node] = lo + excl;
    }
    __syncthreads();
    for (int i = tid; i < cnt; i += 256) {
        unsigned v = pk[i];
        int p = atomicAdd(&curL[v & 127u], 1);
        colL[p] = (int)(v >> 7);
    }
    __syncthreads();
    for (int i = tid; i < cnt; i += 256) col[lo + i] = colL[i];
}

// ======================= weight packing (perm-aware) =======================

__global__ void pack_W_all(const float* __restrict__ c1W2, const float* __restrict__ csW1,
                           const float* __restrict__ csW2, unsigned short* __restrict__ Wp,
                           int NL) {
    int slot = blockIdx.x >> 6;
    int r = (blockIdx.x & 63) * 256 + threadIdx.x;   // 0..16383
    const float* W = (slot == 0) ? c1W2
                   : (slot <= NL ? csW1 + (size_t)(slot - 1) * 16384
                                 : csW2 + (size_t)(slot - 1 - NL) * 16384);
    int j = r & 7, lane = (r >> 3) & 63, nt = (r >> 9) & 7, ks = (r >> 12) & 3;
    int u = ks * 32 + (lane >> 4) * 8 + j;
    int k = (u & 7) * 16 + (u >> 3);                 // pi(u)
    int n = nt * 16 + (lane & 15);
    Wp[(size_t)slot * 16384 + r] = (unsigned short)f2bf(W[k * 128 + n]);
}

// ======================= layer 1 (input dim = 2) =======================

__global__ void agg2(const float* __restrict__ x, const int* __restrict__ rowptr,
                     const int* __restrict__ col, float* __restrict__ sum2, int N) {
    int n = blockIdx.x * 256 + threadIdx.x;
    if (n >= N) return;
    const float2* x2 = (const float2*)x;
    float2 self = x2[n];
    float ax = self.x, ay = self.y;
    int e0 = rowptr[n], e1 = rowptr[n + 1];
    for (int j = e0; j < e1; ++j) {
        float2 v = x2[col[j]];
        ax += v.x;
        ay += v.y;
    }
    sum2[2 * n] = ax;
    sum2[2 * n + 1] = ay;
}

__global__ void mlp1a(const float* __restrict__ sum2, const float* __restrict__ W1,
                      const float* __restrict__ b1, unsigned short* __restrict__ out, int N) {
    int idx = blockIdx.x * 256 + threadIdx.x;
    if (idx >= N * 128) return;
    int n = idx >> 7, p = idx & 127;
    int c = (p & 7) * 16 + (p >> 3);
    float v = fmaf(sum2[2 * n], W1[c], fmaf(sum2[2 * n + 1], W1[128 + c], b1[c]));
    out[idx] = (unsigned short)f2bf(fmaxf(v, 0.f));
}

// ======================= aggregation: 4 nodes/wave, 16x unrolled ============

__device__ __forceinline__ void addrow(float* acc, uint4 v) {
    acc[0] += bflo(v.x); acc[1] += bfhi(v.x);
    acc[2] += bflo(v.y); acc[3] += bfhi(v.y);
    acc[4] += bflo(v.z); acc[5] += bfhi(v.z);
    acc[6] += bflo(v.w); acc[7] += bfhi(v.w);
}

__global__ void aggH_bf16(const uint4* __restrict__ h4, const int* __restrict__ rowptr,
                          const int* __restrict__ col, uint4* __restrict__ out4, int N) {
    int wave = (blockIdx.x * blockDim.x + threadIdx.x) >> 6;
    int lane = threadIdx.x & 63;
    int sub = lane >> 4, sl = lane & 15;
    int n = wave * 4 + sub;
    if (n >= N) return;
    size_t base = (size_t)n * 16 + sl;
    uint4 self = h4[base];
    float acc[8];
    acc[0] = bflo(self.x); acc[1] = bfhi(self.x);
    acc[2] = bflo(self.y); acc[3] = bfhi(self.y);
    acc[4] = bflo(self.z); acc[5] = bfhi(self.z);
    acc[6] = bflo(self.w); acc[7] = bfhi(self.w);
    int e0 = rowptr[n], e1 = rowptr[n + 1];
    int j = e0;
    for (; j + 16 <= e1; j += 16) {
        int s[16];
#pragma unroll
        for (int t = 0; t < 16; ++t) s[t] = col[j + t];
        uint4 v[16];
#pragma unroll
        for (int t = 0; t < 16; ++t) v[t] = h4[(size_t)s[t] * 16 + sl];
#pragma unroll
        for (int t = 0; t < 16; ++t) addrow(acc, v[t]);
    }
    for (; j + 8 <= e1; j += 8) {
        int s[8];
#pragma unroll
        for (int t = 0; t < 8; ++t) s[t] = col[j + t];
        uint4 v[8];
#pragma unroll
        for (int t = 0; t < 8; ++t) v[t] = h4[(size_t)s[t] * 16 + sl];
#pragma unroll
        for (int t = 0; t < 8; ++t) addrow(acc, v[t]);
    }
    for (; j < e1; ++j) addrow(acc, h4[(size_t)col[j] * 16 + sl]);
    out4[base] = pack8bf(acc);
}

// ======================= fused GIN MLP (128 rows/block, 4 waves) ============

__launch_bounds__(256)
__global__ void gin_mlp(const unsigned short* __restrict__ A,
                        const unsigned short* __restrict__ W1p, const float* __restrict__ b1,
                        const unsigned short* __restrict__ W2p, const float* __restrict__ b2,
                        const float* __restrict__ gamma, const float* __restrict__ beta,
                        const float* __restrict__ mean, const float* __restrict__ var,
                        unsigned short* __restrict__ out, int N) {
    __shared__ unsigned short hbuf[4][32][136];   // 272B row stride: 2-way alias (free)
    int wave = threadIdx.x >> 6, lane = threadIdx.x & 63;
    int row0 = blockIdx.x * 128 + wave * 32;
    if (row0 >= N) return;
    int m = lane & 15, q = lane >> 4;
    int ra = row0 + m;      if (ra > N - 1) ra = N - 1;
    int rb = row0 + 16 + m; if (rb > N - 1) rb = N - 1;

    short8 a0[4], a1[4];
#pragma unroll
    for (int ks = 0; ks < 4; ++ks) {
        a0[ks] = *(const short8*)&A[(size_t)ra * 128 + ks * 32 + q * 8];
        a1[ks] = *(const short8*)&A[(size_t)rb * 128 + ks * 32 + q * 8];
    }

    floatx4 c0[8], c1[8];
#pragma unroll
    for (int nt = 0; nt < 8; ++nt) {
        c0[nt] = (floatx4){0.f, 0.f, 0.f, 0.f};
        c1[nt] = (floatx4){0.f, 0.f, 0.f, 0.f};
    }
#pragma unroll
    for (int nt = 0; nt < 8; ++nt) {
        short8 w0 = *(const short8*)&W1p[((0 * 8 + nt) * 64 + lane) * 8];
        short8 w1 = *(const short8*)&W1p[((1 * 8 + nt) * 64 + lane) * 8];
        short8 w2 = *(const short8*)&W1p[((2 * 8 + nt) * 64 + lane) * 8];
        short8 w3 = *(const short8*)&W1p[((3 * 8 + nt) * 64 + lane) * 8];
        c0[nt] = __builtin_amdgcn_mfma_f32_16x16x32_bf16(a0[0], w0, c0[nt], 0, 0, 0);
        c1[nt] = __builtin_amdgcn_mfma_f32_16x16x32_bf16(a1[0], w0, c1[nt], 0, 0, 0);
        c0[nt] = __builtin_amdgcn_mfma_f32_16x16x32_bf16(a0[1], w1, c0[nt], 0, 0, 0);
        c1[nt] = __builtin_amdgcn_mfma_f32_16x16x32_bf16(a1[1], w1, c1[nt], 0, 0, 0);
        c0[nt] = __builtin_amdgcn_mfma_f32_16x16x32_bf16(a0[2], w2, c0[nt], 0, 0, 0);
        c1[nt] = __builtin_amdgcn_mfma_f32_16x16x32_bf16(a1[2], w2, c1[nt], 0, 0, 0);
        c0[nt] = __builtin_amdgcn_mfma_f32_16x16x32_bf16(a0[3], w3, c0[nt], 0, 0, 0);
        c1[nt] = __builtin_amdgcn_mfma_f32_16x16x32_bf16(a1[3], w3, c1[nt], 0, 0, 0);
    }

    float b1v[8];
#pragma unroll
    for (int nt = 0; nt < 8; ++nt) b1v[nt] = b1[nt * 16 + m];
#pragma unroll
    for (int rg = 0; rg < 4; ++rg) {
        float v0[8], v1[8];
#pragma unroll
        for (int nt = 0; nt < 8; ++nt) {
            v0[nt] = fmaxf(c0[nt][rg] + b1v[nt], 0.f);
            v1[nt] = fmaxf(c1[nt][rg] + b1v[nt], 0.f);
        }
        *(uint4*)&hbuf[wave][q * 4 + rg][m * 8] = pack8bf(v0);
        *(uint4*)&hbuf[wave][16 + q * 4 + rg][m * 8] = pack8bf(v1);
    }

    short8 d0[4], d1[4];
#pragma unroll
    for (int ks = 0; ks < 4; ++ks) {
        d0[ks] = *(const short8*)&hbuf[wave][m][ks * 32 + q * 8];
        d1[ks] = *(const short8*)&hbuf[wave][16 + m][ks * 32 + q * 8];
    }

    floatx4 e0[8], e1[8];
#pragma unroll
    for (int nt = 0; nt < 8; ++nt) {
        e0[nt] = (floatx4){0.f, 0.f, 0.f, 0.f};
        e1[nt] = (floatx4){0.f, 0.f, 0.f, 0.f};
    }
#pragma unroll
    for (int nt = 0; nt < 8; ++nt) {
        short8 w0 = *(const short8*)&W2p[((0 * 8 + nt) * 64 + lane) * 8];
        short8 w1 = *(const short8*)&W2p[((1 * 8 + nt) * 64 + lane) * 8];
        short8 w2 = *(const short8*)&W2p[((2 * 8 + nt) * 64 + lane) * 8];
        short8 w3 = *(const short8*)&W2p[((3 * 8 + nt) * 64 + lane) * 8];
        e0[nt] = __builtin_amdgcn_mfma_f32_16x16x32_bf16(d0[0], w0, e0[nt], 0, 0, 0);
        e1[nt] = __builtin_amdgcn_mfma_f32_16x16x32_bf16(d1[0], w0, e1[nt], 0, 0, 0);
        e0[nt] = __builtin_amdgcn_mfma_f32_16x16x32_bf16(d0[1], w1, e0[nt], 0, 0, 0);
        e1[nt] = __builtin_amdgcn_mfma_f32_16x16x32_bf16(d1[1], w1, e1[nt], 0, 0, 0);
        e0[nt] = __builtin_amdgcn_mfma_f32_16x16x32_bf16(d0[2], w2, e0[nt], 0, 0, 0);
        e1[nt] = __builtin_amdgcn_mfma_f32_16x16x32_bf16(d1[2], w2, e1[nt], 0, 0, 0);
        e0[nt] = __builtin_amdgcn_mfma_f32_16x16x32_bf16(d0[3], w3, e0[nt], 0, 0, 0);
        e1[nt] = __builtin_amdgcn_mfma_f32_16x16x32_bf16(d1[3], w3, e1[nt], 0, 0, 0);
    }

    float b2v[8], scl[8], shf[8];
#pragma unroll
    for (int nt = 0; nt < 8; ++nt) {
        int c = nt * 16 + m;
        b2v[nt] = b2[c];
        float s = gamma[c] * rsqrtf(var[c] + 1e-5f);
        scl[nt] = s;
        shf[nt] = beta[c] - mean[c] * s;
    }
#pragma unroll
    for (int rg = 0; rg < 4; ++rg) {
        int r0 = row0 + q * 4 + rg;
        int r1 = row0 + 16 + q * 4 + rg;
        float v0[8], v1[8];
#pragma unroll
        for (int nt = 0; nt < 8; ++nt) {
            v0[nt] = fmaf(fmaxf(e0[nt][rg] + b2v[nt], 0.f), scl[nt], shf[nt]);
            v1[nt] = fmaf(fmaxf(e1[nt][rg] + b2v[nt], 0.f), scl[nt], shf[nt]);
        }
        if (r0 < N) *(uint4*)&out[(size_t)r0 * 128 + m * 8] = pack8bf(v0);
        if (r1 < N) *(uint4*)&out[(size_t)r1 * 128 + m * 8] = pack8bf(v1);
    }
}

// ======================= layer-1 single GEMM (128 rows/block) ===============

__launch_bounds__(256)
__global__ void gemm_one(const unsigned short* __restrict__ A,
                         const unsigned short* __restrict__ Wp,
                         const float* __restrict__ bias,
                         const float* __restrict__ gamma, const float* __restrict__ beta,
                         const float* __restrict__ mean, const float* __restrict__ var,
                         unsigned short* __restrict__ out, int N) {
    int wave = threadIdx.x >> 6, lane = threadIdx.x & 63;
    int row0 = blockIdx.x * 128 + wave * 32;
    if (row0 >= N) return;
    int m = lane & 15, q = lane >> 4;
    int ra = row0 + m;      if (ra > N - 1) ra = N - 1;
    int rb = row0 + 16 + m; if (rb > N - 1) rb = N - 1;

    short8 a0[4], a1[4];
#pragma unroll
    for (int ks = 0; ks < 4; ++ks) {
        a0[ks] = *(const short8*)&A[(size_t)ra * 128 + ks * 32 + q * 8];
        a1[ks] = *(const short8*)&A[(size_t)rb * 128 + ks * 32 + q * 8];
    }
    floatx4 c0[8], c1[8];
#pragma unroll
    for (int nt = 0; nt < 8; ++nt) {
        c0[nt] = (floatx4){0.f, 0.f, 0.f, 0.f};
        c1[nt] = (floatx4){0.f, 0.f, 0.f, 0.f};
    }
#pragma unroll
    for (int nt = 0; nt < 8; ++nt) {
        short8 w0 = *(const short8*)&Wp[((0 * 8 + nt) * 64 + lane) * 8];
        short8 w1 = *(const short8*)&Wp[((1 * 8 + nt) * 64 + lane) * 8];
        short8 w2 = *(const short8*)&Wp[((2 * 8 + nt) * 64 + lane) * 8];
        short8 w3 = *(const short8*)&Wp[((3 * 8 + nt) * 64 + lane) * 8];
        c0[nt] = __builtin_amdgcn_mfma_f32_16x16x32_bf16(a0[0], w0, c0[nt], 0, 0, 0);
        c1[nt] = __builtin_amdgcn_mfma_f32_16x16x32_bf16(a1[0], w0, c1[nt], 0, 0, 0);
        c0[nt] = __builtin_amdgcn_mfma_f32_16x16x32_bf16(a0[1], w1, c0[nt], 0, 0, 0);
        c1[nt] = __builtin_amdgcn_mfma_f32_16x16x32_bf16(a1[1], w1, c1[nt], 0, 0, 0);
        c0[nt] = __builtin_amdgcn_mfma_f32_16x16x32_bf16(a0[2], w2, c0[nt], 0, 0, 0);
        c1[nt] = __builtin_amdgcn_mfma_f32_16x16x32_bf16(a1[2], w2, c1[nt], 0, 0, 0);
        c0[nt] = __builtin_amdgcn_mfma_f32_16x16x32_bf16(a0[3], w3, c0[nt], 0, 0, 0);
        c1[nt] = __builtin_amdgcn_mfma_f32_16x16x32_bf16(a1[3], w3, c1[nt], 0, 0, 0);
    }
    float bv[8], scl[8], shf[8];
#pragma unroll
    for (int nt = 0; nt < 8; ++nt) {
        int c = nt * 16 + m;
        bv[nt] = bias[c];
        float s = gamma[c] * rsqrtf(var[c] + 1e-5f);
        scl[nt] = s;
        shf[nt] = beta[c] - mean[c] * s;
    }
#pragma unroll
    for (int rg = 0; rg < 4; ++rg) {
        int r0 = row0 + q * 4 + rg;
        int r1 = row0 + 16 + q * 4 + rg;
        float v0[8], v1[8];
#pragma unroll
        for (int nt = 0; nt < 8; ++nt) {
            v0[nt] = fmaf(fmaxf(c0[nt][rg] + bv[nt], 0.f), scl[nt], shf[nt]);
            v1[nt] = fmaf(fmaxf(c1[nt][rg] + bv[nt], 0.f), scl[nt], shf[nt]);
        }
        if (r0 < N) *(uint4*)&out[(size_t)r0 * 128 + m * 8] = pack8bf(v0);
        if (r1 < N) *(uint4*)&out[(size_t)r1 * 128 + m * 8] = pack8bf(v1);
    }
}

// ======================= pooling: parallel partial sums + head ==============

__global__ void pool_partial(const unsigned short* __restrict__ h,
                             const int* __restrict__ batch,
                             float* __restrict__ pooled, int N) {
    int c = threadIdx.x;              // 0..127
    int n0 = blockIdx.x * 32;
    int n1 = n0 + 32; if (n1 > N) n1 = N;
    if (n0 >= N) return;
    int cg = batch[n0];
    float acc = 0.f;
    for (int n = n0; n < n1; ++n) {
        int g = batch[n];
        if (g != cg) {
            atomicAdd(&pooled[(size_t)cg * 128 + c], acc);
            acc = 0.f;
            cg = g;
        }
        acc += bf2f(h[(size_t)n * 128 + c]);
    }
    atomicAdd(&pooled[(size_t)cg * 128 + c], acc);
}

__global__ void head(const float* __restrict__ pooled,
                     const float* __restrict__ lin1W, const float* __restrict__ lin1b,
                     const float* __restrict__ lin2W, const float* __restrict__ lin2b,
                     float* __restrict__ out) {
    int g = blockIdx.x;
    int c = threadIdx.x;  // 0..127
    __shared__ float pl[128];
    pl[c] = pooled[(size_t)g * 128 + c];
    __syncthreads();

    float o = lin1b[c];
    for (int k = 0; k < 128; ++k) {
        int ko = (k & 7) * 16 + (k >> 3);   // orig col held at permuted position k
        o = fmaf(pl[k], lin1W[ko * 128 + c], o);
    }
    o = fmaxf(o, 0.f) * lin2W[c];

    __shared__ float red[128];
    red[c] = o;
    __syncthreads();
    for (int off = 64; off > 0; off >>= 1) {
        if (c < off) red[c] += red[c + off];
        __syncthreads();
    }
    if (c == 0) out[g] = red[0] + lin2b[0];
}

// ---------------------------------------------------------------------------

extern "C" void kernel_launch(void* const* d_in, const int* in_sizes, int n_in,
                              void* d_out, int out_size, void* d_ws, size_t ws_size,
                              hipStream_t stream) {
    const float* x     = (const float*)d_in[0];
    const int*   ei    = (const int*)d_in[1];
    const int*   batch = (const int*)d_in[2];
    const float* c1W1  = (const float*)d_in[3];
    const float* c1b1  = (const float*)d_in[4];
    const float* c1W2  = (const float*)d_in[5];
    const float* c1b2  = (const float*)d_in[6];
    const float* c1g   = (const float*)d_in[7];
    const float* c1be  = (const float*)d_in[8];
    const float* c1m   = (const float*)d_in[9];
    const float* c1v   = (const float*)d_in[10];
    const float* csW1  = (const float*)d_in[11];
    const float* csb1  = (const float*)d_in[12];
    const float* csW2  = (const float*)d_in[13];
    const float* csb2  = (const float*)d_in[14];
    const float* csg   = (const float*)d_in[15];
    const float* csbe  = (const float*)d_in[16];
    const float* csm   = (const float*)d_in[17];
    const float* csv   = (const float*)d_in[18];
    const float* lin1W = (const float*)d_in[19];
    const float* lin1b = (const float*)d_in[20];
    const float* lin2W = (const float*)d_in[21];
    const float* lin2b = (const float*)d_in[22];

    const int N = in_sizes[0] / 2;
    const int E = in_sizes[1] / 2;
    const int G = out_size;
    const int NL = in_sizes[11] / (128 * 128);  // 4
    const int nb = (N + 127) >> 7;              // buckets of 128 nodes

    char* ws = (char*)d_ws;
    size_t HS = (size_t)N * 128 * sizeof(unsigned short);      // bf16 feature plane
    unsigned short* h   = (unsigned short*)(ws);
    unsigned short* sum = (unsigned short*)(ws + HS);
    unsigned short* tmp = (unsigned short*)(ws + 2 * HS);
    char* p = ws + 3 * HS;
    float* sum2 = (float*)p;                 p += (((size_t)N * 2 * 4 + 15) / 16) * 16;
    unsigned short* Wp = (unsigned short*)p; p += ((9 * 16384 * 2 + 15) / 16) * 16;
    int* rowptr = (int*)p;                   p += (((size_t)(N + 1) * 4 + 15) / 16) * 16;
    int* col = (int*)p;                      p += (((size_t)E * 4 + 15) / 16) * 16;
    unsigned* staging = (unsigned*)p;        p += (((size_t)E * 4 + 15) / 16) * 16;
    int* bcnt = (int*)p;                     p += 512 * 4;
    int* boff = (int*)p;                     p += 513 * 4;
    int* bcur = (int*)p;                     p += 512 * 4;
    float* pooled = (float*)p;               p += (size_t)G * 128 * 4;

    const int* srcI = ei;
    const int* dstI = ei + E;

    const int NB = (N + 255) / 256;
    const int ET = (E + 4095) / 4096;

    // CSR build (bucketed, no scattered global writes)
    (void)hipMemsetAsync(bcnt, 0, 512 * 4, stream);
    (void)hipMemsetAsync(pooled, 0, (size_t)G * 128 * 4, stream);
    bucket_hist<<<ET, 256, 0, stream>>>(dstI, bcnt, E, nb);
    scan_buckets<<<1, 512, 0, stream>>>(bcnt, boff, bcur, rowptr, nb, N);
    bucket_scatter<<<ET, 256, 0, stream>>>(srcI, dstI, bcur, staging, E, nb);
    bucket_build<<<nb, 256, 0, stream>>>(staging, boff, rowptr, col, N);

    // weight packing
    pack_W_all<<<(1 + 2 * NL) * 64, 256, 0, stream>>>(c1W2, csW1, csW2, Wp, NL);

    const int GEMMB = (N + 127) / 128;
    const int AGGB = ((N + 3) / 4 + 3) / 4;

    // layer 1 (input dim 2)
    agg2<<<NB, 256, 0, stream>>>(x, rowptr, col, sum2, N);
    mlp1a<<<(N * 128 + 255) / 256, 256, 0, stream>>>(sum2, c1W1, c1b1, tmp, N);
    gemm_one<<<GEMMB, 256, 0, stream>>>(tmp, Wp, c1b2, c1g, c1be, c1m, c1v, h, N);

    // layers 2..5
    for (int i = 0; i < NL; ++i) {
        aggH_bf16<<<AGGB, 256, 0, stream>>>((const uint4*)h, rowptr, col, (uint4*)sum, N);
        gin_mlp<<<GEMMB, 256, 0, stream>>>(sum,
                                           Wp + (size_t)(1 + i) * 16384, csb1 + i * 128,
                                           Wp + (size_t)(1 + NL + i) * 16384, csb2 + i * 128,
                                           csg + i * 128, csbe + i * 128, csm + i * 128,
                                           csv + i * 128, h, N);
    }

    // pooling + head
    pool_partial<<<(N + 31) / 32, 128, 0, stream>>>(h, batch, pooled, N);
    head<<<G, 128, 0, stream>>>(pooled, lin1W, lin1b, lin2W, lin2b, (float*)d_out);
}

// Round 11
// 401.374 us; speedup vs baseline: 1.1383x; 1.0622x over previous
//
#include <hip/hip_runtime.h>

// ---------------------------------------------------------------------------
// GIN inference, round 10:
//  - aggH restored to R5's 8x unroll (unroll-16 cost ~20us: VGPR pressure cut
//    resident waves on the TLP-bound gather)
//  - gin_mlp / gemm_one: 1-wave (64-thread) blocks, 32 rows each -> 1563
//    blocks (6.1/CU) vs 391 (1.5/CU): kills CU-count tail quantization.
//    (hbuf was already wave-private; instruction stream unchanged.)
// ---------------------------------------------------------------------------

typedef __attribute__((ext_vector_type(8))) short short8;   // 8 bf16 (4 VGPRs)
typedef __attribute__((ext_vector_type(4))) float floatx4;  // 4 fp32 acc

__device__ __forceinline__ unsigned f2bf(float f) {
    unsigned u = __float_as_uint(f);
    return (u + 0x7fffu + ((u >> 16) & 1u)) >> 16;   // RNE
}
__device__ __forceinline__ float bf2f(unsigned short b) {
    return __uint_as_float(((unsigned)b) << 16);
}
__device__ __forceinline__ float bflo(unsigned u) { return __uint_as_float(u << 16); }
__device__ __forceinline__ float bfhi(unsigned u) { return __uint_as_float(u & 0xffff0000u); }

__device__ __forceinline__ uint4 pack8bf(const float* v) {
    uint4 o;
    o.x = f2bf(v[0]) | (f2bf(v[1]) << 16);
    o.y = f2bf(v[2]) | (f2bf(v[3]) << 16);
    o.z = f2bf(v[4]) | (f2bf(v[5]) << 16);
    o.w = f2bf(v[6]) | (f2bf(v[7]) << 16);
    return o;
}

// ======================= bucketed CSR build =======================

__global__ void bucket_hist(const int* __restrict__ dstA, int* __restrict__ bcnt,
                            int E, int nb) {
    __shared__ int hist[512];
    int tid = threadIdx.x;
    int start = blockIdx.x * 4096;
    for (int i = tid; i < 512; i += 256) hist[i] = 0;
    __syncthreads();
#pragma unroll
    for (int t = 0; t < 16; ++t) {
        int e = start + t * 256 + tid;
        if (e < E) atomicAdd(&hist[dstA[e] >> 7], 1);
    }
    __syncthreads();
    for (int i = tid; i < nb; i += 256)
        if (hist[i]) atomicAdd(&bcnt[i], hist[i]);
}

__global__ void scan_buckets(const int* __restrict__ bcnt, int* __restrict__ boff,
                             int* __restrict__ bcur, int* __restrict__ rowptr,
                             int nb, int N) {
    __shared__ int sa[512], sb[512];
    int t = threadIdx.x;
    sa[t] = (t < nb) ? bcnt[t] : 0;
    __syncthreads();
    int* ps = sa;
    int* pd = sb;
    for (int o = 1; o < 512; o <<= 1) {
        pd[t] = ps[t] + ((t >= o) ? ps[t - o] : 0);
        __syncthreads();
        int* tmp = ps; ps = pd; pd = tmp;
    }
    if (t <= nb) boff[t] = (t == 0) ? 0 : ps[t - 1];
    if (t < nb) bcur[t] = (t == 0) ? 0 : ps[t - 1];
    if (t == 0) rowptr[N] = ps[nb - 1];
}

__global__ void bucket_scatter(const int* __restrict__ srcA, const int* __restrict__ dstA,
                               int* __restrict__ bcur, unsigned* __restrict__ staging,
                               int E, int nb) {
    __shared__ int hist[512];
    __shared__ int sa[512], sb[512];
    __shared__ int toff[513];
    __shared__ int gbase[512];
    __shared__ unsigned pk[4096];
    __shared__ unsigned short bkt[4096];
    int tid = threadIdx.x;
    int start = blockIdx.x * 4096;
    for (int i = tid; i < 512; i += 256) hist[i] = 0;
    __syncthreads();
    int bidx[16], rank[16];
    unsigned pval[16];
#pragma unroll
    for (int t = 0; t < 16; ++t) {
        int e = start + t * 256 + tid;
        bidx[t] = -1;
        if (e < E) {
            int d = dstA[e];
            int s = srcA[e];
            int b = d >> 7;
            bidx[t] = b;
            rank[t] = atomicAdd(&hist[b], 1);
            pval[t] = ((unsigned)s << 7) | (unsigned)(d & 127);
        }
    }
    __syncthreads();
    sa[tid] = hist[tid];
    sa[tid + 256] = hist[tid + 256];
    __syncthreads();
    int* ps = sa;
    int* pd = sb;
    for (int o = 1; o < 512; o <<= 1) {
        pd[tid] = ps[tid] + ((tid >= o) ? ps[tid - o] : 0);
        int j2 = tid + 256;
        pd[j2] = ps[j2] + ((j2 >= o) ? ps[j2 - o] : 0);
        __syncthreads();
        int* tmp = ps; ps = pd; pd = tmp;
    }
    toff[tid + 1] = ps[tid];
    toff[tid + 257] = ps[tid + 256];
    if (tid == 0) toff[0] = 0;
    __syncthreads();
    for (int b = tid; b < nb; b += 256) {
        int c = hist[b];
        gbase[b] = c ? atomicAdd(&bcur[b], c) : 0;
    }
#pragma unroll
    for (int t = 0; t < 16; ++t)
        if (bidx[t] >= 0) {
            int pos = toff[bidx[t]] + rank[t];
            pk[pos] = pval[t];
            bkt[pos] = (unsigned short)bidx[t];
        }
    __syncthreads();
    int total = toff[512];
    for (int i = tid; i < total; i += 256) {
        int b = bkt[i];
        staging[gbase[b] + (i - toff[b])] = pk[i];
    }
}

__global__ void bucket_build(const unsigned* __restrict__ staging, const int* __restrict__ boff,
                             int* __restrict__ rowptr, int* __restrict__ col, int N) {
    __shared__ int deg[128], sca[128], scb[128], curL[128];
    __shared__ unsigned pk[4096];
    __shared__ int colL[4096];
    int b = blockIdx.x, tid = threadIdx.x;
    int lo = boff[b], hi = boff[b + 1];
    int cnt = hi - lo;
    if (cnt > 4096) cnt = 4096;
    for (int i = tid; i < cnt; i += 256) pk[i] = staging[lo + i];
    if (tid < 128) deg[tid] = 0;
    __syncthreads();
    for (int i = tid; i < cnt; i += 256) atomicAdd(&deg[pk[i] & 127u], 1);
    __syncthreads();
    if (tid < 128) sca[tid] = deg[tid];
    __syncthreads();
    int* ps = sca;
    int* pd = scb;
    for (int o = 1; o < 128; o <<= 1) {
        if (tid < 128) pd[tid] = ps[tid] + ((tid >= o) ? ps[tid - o] : 0);
        __syncthreads();
        int* tmp = ps; ps = pd; pd = tmp;
    }
    if (tid < 128) {
        int excl = tid ? ps[tid - 1] : 0;
        curL[tid] = excl;
        int node = b * 128 + tid;
        if (node < N) rowptr[node] = lo + excl;
    }
    __syncthreads();
    for (int i = tid; i < cnt; i += 256) {
        unsigned v = pk[i];
        int p = atomicAdd(&curL[v & 127u], 1);
        colL[p] = (int)(v >> 7);
    }
    __syncthreads();
    for (int i = tid; i < cnt; i += 256) col[lo + i] = colL[i];
}

// ======================= weight packing (perm-aware) =======================

__global__ void pack_W_all(const float* __restrict__ c1W2, const float* __restrict__ csW1,
                           const float* __restrict__ csW2, unsigned short* __restrict__ Wp,
                           int NL) {
    int slot = blockIdx.x >> 6;
    int r = (blockIdx.x & 63) * 256 + threadIdx.x;   // 0..16383
    const float* W = (slot == 0) ? c1W2
                   : (slot <= NL ? csW1 + (size_t)(slot - 1) * 16384
                                 : csW2 + (size_t)(slot - 1 - NL) * 16384);
    int j = r & 7, lane = (r >> 3) & 63, nt = (r >> 9) & 7, ks = (r >> 12) & 3;
    int u = ks * 32 + (lane >> 4) * 8 + j;
    int k = (u & 7) * 16 + (u >> 3);                 // pi(u)
    int n = nt * 16 + (lane & 15);
    Wp[(size_t)slot * 16384 + r] = (unsigned short)f2bf(W[k * 128 + n]);
}

// ======================= layer 1 (input dim = 2) =======================

__global__ void agg2(const float* __restrict__ x, const int* __restrict__ rowptr,
                     const int* __restrict__ col, float* __restrict__ sum2, int N) {
    int n = blockIdx.x * 256 + threadIdx.x;
    if (n >= N) return;
    const float2* x2 = (const float2*)x;
    float2 self = x2[n];
    float ax = self.x, ay = self.y;
    int e0 = rowptr[n], e1 = rowptr[n + 1];
    for (int j = e0; j < e1; ++j) {
        float2 v = x2[col[j]];
        ax += v.x;
        ay += v.y;
    }
    sum2[2 * n] = ax;
    sum2[2 * n + 1] = ay;
}

__global__ void mlp1a(const float* __restrict__ sum2, const float* __restrict__ W1,
                      const float* __restrict__ b1, unsigned short* __restrict__ out, int N) {
    int idx = blockIdx.x * 256 + threadIdx.x;
    if (idx >= N * 128) return;
    int n = idx >> 7, p = idx & 127;
    int c = (p & 7) * 16 + (p >> 3);
    float v = fmaf(sum2[2 * n], W1[c], fmaf(sum2[2 * n + 1], W1[128 + c], b1[c]));
    out[idx] = (unsigned short)f2bf(fmaxf(v, 0.f));
}

// ======================= aggregation: 4 nodes/wave, 8x unrolled (R5) ========

__device__ __forceinline__ void addrow(float* acc, uint4 v) {
    acc[0] += bflo(v.x); acc[1] += bfhi(v.x);
    acc[2] += bflo(v.y); acc[3] += bfhi(v.y);
    acc[4] += bflo(v.z); acc[5] += bfhi(v.z);
    acc[6] += bflo(v.w); acc[7] += bfhi(v.w);
}

__global__ void aggH_bf16(const uint4* __restrict__ h4, const int* __restrict__ rowptr,
                          const int* __restrict__ col, uint4* __restrict__ out4, int N) {
    int wave = (blockIdx.x * blockDim.x + threadIdx.x) >> 6;
    int lane = threadIdx.x & 63;
    int sub = lane >> 4, sl = lane & 15;
    int n = wave * 4 + sub;
    if (n >= N) return;
    size_t base = (size_t)n * 16 + sl;
    uint4 self = h4[base];
    float acc[8];
    acc[0] = bflo(self.x); acc[1] = bfhi(self.x);
    acc[2] = bflo(self.y); acc[3] = bfhi(self.y);
    acc[4] = bflo(self.z); acc[5] = bfhi(self.z);
    acc[6] = bflo(self.w); acc[7] = bfhi(self.w);
    int e0 = rowptr[n], e1 = rowptr[n + 1];
    int j = e0;
    for (; j + 8 <= e1; j += 8) {
        int s[8];
#pragma unroll
        for (int t = 0; t < 8; ++t) s[t] = col[j + t];
        uint4 v[8];
#pragma unroll
        for (int t = 0; t < 8; ++t) v[t] = h4[(size_t)s[t] * 16 + sl];
#pragma unroll
        for (int t = 0; t < 8; ++t) addrow(acc, v[t]);
    }
    for (; j + 4 <= e1; j += 4) {
        int s0 = col[j], s1 = col[j + 1], s2 = col[j + 2], s3 = col[j + 3];
        uint4 v0 = h4[(size_t)s0 * 16 + sl];
        uint4 v1 = h4[(size_t)s1 * 16 + sl];
        uint4 v2 = h4[(size_t)s2 * 16 + sl];
        uint4 v3 = h4[(size_t)s3 * 16 + sl];
        addrow(acc, v0);
        addrow(acc, v1);
        addrow(acc, v2);
        addrow(acc, v3);
    }
    for (; j < e1; ++j) addrow(acc, h4[(size_t)col[j] * 16 + sl]);
    out4[base] = pack8bf(acc);
}

// ======================= fused GIN MLP (1 wave/block, 32 rows) ==============

__launch_bounds__(64)
__global__ void gin_mlp(const unsigned short* __restrict__ A,
                        const unsigned short* __restrict__ W1p, const float* __restrict__ b1,
                        const unsigned short* __restrict__ W2p, const float* __restrict__ b2,
                        const float* __restrict__ gamma, const float* __restrict__ beta,
                        const float* __restrict__ mean, const float* __restrict__ var,
                        unsigned short* __restrict__ out, int N) {
    __shared__ unsigned short hbuf[32][136];   // 272B row stride: 2-way alias (free)
    int lane = threadIdx.x & 63;
    int row0 = blockIdx.x * 32;
    if (row0 >= N) return;
    int m = lane & 15, q = lane >> 4;
    int ra = row0 + m;      if (ra > N - 1) ra = N - 1;
    int rb = row0 + 16 + m; if (rb > N - 1) rb = N - 1;

    short8 a0[4], a1[4];
#pragma unroll
    for (int ks = 0; ks < 4; ++ks) {
        a0[ks] = *(const short8*)&A[(size_t)ra * 128 + ks * 32 + q * 8];
        a1[ks] = *(const short8*)&A[(size_t)rb * 128 + ks * 32 + q * 8];
    }

    floatx4 c0[8], c1[8];
#pragma unroll
    for (int nt = 0; nt < 8; ++nt) {
        c0[nt] = (floatx4){0.f, 0.f, 0.f, 0.f};
        c1[nt] = (floatx4){0.f, 0.f, 0.f, 0.f};
    }
#pragma unroll
    for (int nt = 0; nt < 8; ++nt) {
        short8 w0 = *(const short8*)&W1p[((0 * 8 + nt) * 64 + lane) * 8];
        short8 w1 = *(const short8*)&W1p[((1 * 8 + nt) * 64 + lane) * 8];
        short8 w2 = *(const short8*)&W1p[((2 * 8 + nt) * 64 + lane) * 8];
        short8 w3 = *(const short8*)&W1p[((3 * 8 + nt) * 64 + lane) * 8];
        c0[nt] = __builtin_amdgcn_mfma_f32_16x16x32_bf16(a0[0], w0, c0[nt], 0, 0, 0);
        c1[nt] = __builtin_amdgcn_mfma_f32_16x16x32_bf16(a1[0], w0, c1[nt], 0, 0, 0);
        c0[nt] = __builtin_amdgcn_mfma_f32_16x16x32_bf16(a0[1], w1, c0[nt], 0, 0, 0);
        c1[nt] = __builtin_amdgcn_mfma_f32_16x16x32_bf16(a1[1], w1, c1[nt], 0, 0, 0);
        c0[nt] = __builtin_amdgcn_mfma_f32_16x16x32_bf16(a0[2], w2, c0[nt], 0, 0, 0);
        c1[nt] = __builtin_amdgcn_mfma_f32_16x16x32_bf16(a1[2], w2, c1[nt], 0, 0, 0);
        c0[nt] = __builtin_amdgcn_mfma_f32_16x16x32_bf16(a0[3], w3, c0[nt], 0, 0, 0);
        c1[nt] = __builtin_amdgcn_mfma_f32_16x16x32_bf16(a1[3], w3, c1[nt], 0, 0, 0);
    }

    float b1v[8];
#pragma unroll
    for (int nt = 0; nt < 8; ++nt) b1v[nt] = b1[nt * 16 + m];
#pragma unroll
    for (int rg = 0; rg < 4; ++rg) {
        float v0[8], v1[8];
#pragma unroll
        for (int nt = 0; nt < 8; ++nt) {
            v0[nt] = fmaxf(c0[nt][rg] + b1v[nt], 0.f);
            v1[nt] = fmaxf(c1[nt][rg] + b1v[nt], 0.f);
        }
        *(uint4*)&hbuf[q * 4 + rg][m * 8] = pack8bf(v0);
        *(uint4*)&hbuf[16 + q * 4 + rg][m * 8] = pack8bf(v1);
    }

    short8 d0[4], d1[4];
#pragma unroll
    for (int ks = 0; ks < 4; ++ks) {
        d0[ks] = *(const short8*)&hbuf[m][ks * 32 + q * 8];
        d1[ks] = *(const short8*)&hbuf[16 + m][ks * 32 + q * 8];
    }

    floatx4 e0[8], e1[8];
#pragma unroll
    for (int nt = 0; nt < 8; ++nt) {
        e0[nt] = (floatx4){0.f, 0.f, 0.f, 0.f};
        e1[nt] = (floatx4){0.f, 0.f, 0.f, 0.f};
    }
#pragma unroll
    for (int nt = 0; nt < 8; ++nt) {
        short8 w0 = *(const short8*)&W2p[((0 * 8 + nt) * 64 + lane) * 8];
        short8 w1 = *(const short8*)&W2p[((1 * 8 + nt) * 64 + lane) * 8];
        short8 w2 = *(const short8*)&W2p[((2 * 8 + nt) * 64 + lane) * 8];
        short8 w3 = *(const short8*)&W2p[((3 * 8 + nt) * 64 + lane) * 8];
        e0[nt] = __builtin_amdgcn_mfma_f32_16x16x32_bf16(d0[0], w0, e0[nt], 0, 0, 0);
        e1[nt] = __builtin_amdgcn_mfma_f32_16x16x32_bf16(d1[0], w0, e1[nt], 0, 0, 0);
        e0[nt] = __builtin_amdgcn_mfma_f32_16x16x32_bf16(d0[1], w1, e0[nt], 0, 0, 0);
        e1[nt] = __builtin_amdgcn_mfma_f32_16x16x32_bf16(d1[1], w1, e1[nt], 0, 0, 0);
        e0[nt] = __builtin_amdgcn_mfma_f32_16x16x32_bf16(d0[2], w2, e0[nt], 0, 0, 0);
        e1[nt] = __builtin_amdgcn_mfma_f32_16x16x32_bf16(d1[2], w2, e1[nt], 0, 0, 0);
        e0[nt] = __builtin_amdgcn_mfma_f32_16x16x32_bf16(d0[3], w3, e0[nt], 0, 0, 0);
        e1[nt] = __builtin_amdgcn_mfma_f32_16x16x32_bf16(d1[3], w3, e1[nt], 0, 0, 0);
    }

    float b2v[8], scl[8], shf[8];
#pragma unroll
    for (int nt = 0; nt < 8; ++nt) {
        int c = nt * 16 + m;
        b2v[nt] = b2[c];
        float s = gamma[c] * rsqrtf(var[c] + 1e-5f);
        scl[nt] = s;
        shf[nt] = beta[c] - mean[c] * s;
    }
#pragma unroll
    for (int rg = 0; rg < 4; ++rg) {
        int r0 = row0 + q * 4 + rg;
        int r1 = row0 + 16 + q * 4 + rg;
        float v0[8], v1[8];
#pragma unroll
        for (int nt = 0; nt < 8; ++nt) {
            v0[nt] = fmaf(fmaxf(e0[nt][rg] + b2v[nt], 0.f), scl[nt], shf[nt]);
            v1[nt] = fmaf(fmaxf(e1[nt][rg] + b2v[nt], 0.f), scl[nt], shf[nt]);
        }
        if (r0 < N) *(uint4*)&out[(size_t)r0 * 128 + m * 8] = pack8bf(v0);
        if (r1 < N) *(uint4*)&out[(size_t)r1 * 128 + m * 8] = pack8bf(v1);
    }
}

// ======================= layer-1 single GEMM (1 wave/block, 32 rows) ========

__launch_bounds__(64)
__global__ void gemm_one(const unsigned short* __restrict__ A,
                         const unsigned short* __restrict__ Wp,
                         const float* __restrict__ bias,
                         const float* __restrict__ gamma, const float* __restrict__ beta,
                         const float* __restrict__ mean, const float* __restrict__ var,
                         unsigned short* __restrict__ out, int N) {
    int lane = threadIdx.x & 63;
    int row0 = blockIdx.x * 32;
    if (row0 >= N) return;
    int m = lane & 15, q = lane >> 4;
    int ra = row0 + m;      if (ra > N - 1) ra = N - 1;
    int rb = row0 + 16 + m; if (rb > N - 1) rb = N - 1;

    short8 a0[4], a1[4];
#pragma unroll
    for (int ks = 0; ks < 4; ++ks) {
        a0[ks] = *(const short8*)&A[(size_t)ra * 128 + ks * 32 + q * 8];
        a1[ks] = *(const short8*)&A[(size_t)rb * 128 + ks * 32 + q * 8];
    }
    floatx4 c0[8], c1[8];
#pragma unroll
    for (int nt = 0; nt < 8; ++nt) {
        c0[nt] = (floatx4){0.f, 0.f, 0.f, 0.f};
        c1[nt] = (floatx4){0.f, 0.f, 0.f, 0.f};
    }
#pragma unroll
    for (int nt = 0; nt < 8; ++nt) {
        short8 w0 = *(const short8*)&Wp[((0 * 8 + nt) * 64 + lane) * 8];
        short8 w1 = *(const short8*)&Wp[((1 * 8 + nt) * 64 + lane) * 8];
        short8 w2 = *(const short8*)&Wp[((2 * 8 + nt) * 64 + lane) * 8];
        short8 w3 = *(const short8*)&Wp[((3 * 8 + nt) * 64 + lane) * 8];
        c0[nt] = __builtin_amdgcn_mfma_f32_16x16x32_bf16(a0[0], w0, c0[nt], 0, 0, 0);
        c1[nt] = __builtin_amdgcn_mfma_f32_16x16x32_bf16(a1[0], w0, c1[nt], 0, 0, 0);
        c0[nt] = __builtin_amdgcn_mfma_f32_16x16x32_bf16(a0[1], w1, c0[nt], 0, 0, 0);
        c1[nt] = __builtin_amdgcn_mfma_f32_16x16x32_bf16(a1[1], w1, c1[nt], 0, 0, 0);
        c0[nt] = __builtin_amdgcn_mfma_f32_16x16x32_bf16(a0[2], w2, c0[nt], 0, 0, 0);
        c1[nt] = __builtin_amdgcn_mfma_f32_16x16x32_bf16(a1[2], w2, c1[nt], 0, 0, 0);
        c0[nt] = __builtin_amdgcn_mfma_f32_16x16x32_bf16(a0[3], w3, c0[nt], 0, 0, 0);
        c1[nt] = __builtin_amdgcn_mfma_f32_16x16x32_bf16(a1[3], w3, c1[nt], 0, 0, 0);
    }
    float bv[8], scl[8], shf[8];
#pragma unroll
    for (int nt = 0; nt < 8; ++nt) {
        int c = nt * 16 + m;
        bv[nt] = bias[c];
        float s = gamma[c] * rsqrtf(var[c] + 1e-5f);
        scl[nt] = s;
        shf[nt] = beta[c] - mean[c] * s;
    }
#pragma unroll
    for (int rg = 0; rg < 4; ++rg) {
        int r0 = row0 + q * 4 + rg;
        int r1 = row0 + 16 + q * 4 + rg;
        float v0[8], v1[8];
#pragma unroll
        for (int nt = 0; nt < 8; ++nt) {
            v0[nt] = fmaf(fmaxf(c0[nt][rg] + bv[nt], 0.f), scl[nt], shf[nt]);
            v1[nt] = fmaf(fmaxf(c1[nt][rg] + bv[nt], 0.f), scl[nt], shf[nt]);
        }
        if (r0 < N) *(uint4*)&out[(size_t)r0 * 128 + m * 8] = pack8bf(v0);
        if (r1 < N) *(uint4*)&out[(size_t)r1 * 128 + m * 8] = pack8bf(v1);
    }
}

// ======================= pooling: parallel partial sums + head ==============

__global__ void pool_partial(const unsigned short* __restrict__ h,
                             const int* __restrict__ batch,
                             float* __restrict__ pooled, int N) {
    int c = threadIdx.x;              // 0..127
    int n0 = blockIdx.x * 32;
    int n1 = n0 + 32; if (n1 > N) n1 = N;
    if (n0 >= N) return;
    int cg = batch[n0];
    float acc = 0.f;
    for (int n = n0; n < n1; ++n) {
        int g = batch[n];
        if (g != cg) {
            atomicAdd(&pooled[(size_t)cg * 128 + c], acc);
            acc = 0.f;
            cg = g;
        }
        acc += bf2f(h[(size_t)n * 128 + c]);
    }
    atomicAdd(&pooled[(size_t)cg * 128 + c], acc);
}

__global__ void head(const float* __restrict__ pooled,
                     const float* __restrict__ lin1W, const float* __restrict__ lin1b,
                     const float* __restrict__ lin2W, const float* __restrict__ lin2b,
                     float* __restrict__ out) {
    int g = blockIdx.x;
    int c = threadIdx.x;  // 0..127
    __shared__ float pl[128];
    pl[c] = pooled[(size_t)g * 128 + c];
    __syncthreads();

    float o = lin1b[c];
    for (int k = 0; k < 128; ++k) {
        int ko = (k & 7) * 16 + (k >> 3);   // orig col held at permuted position k
        o = fmaf(pl[k], lin1W[ko * 128 + c], o);
    }
    o = fmaxf(o, 0.f) * lin2W[c];

    __shared__ float red[128];
    red[c] = o;
    __syncthreads();
    for (int off = 64; off > 0; off >>= 1) {
        if (c < off) red[c] += red[c + off];
        __syncthreads();
    }
    if (c == 0) out[g] = red[0] + lin2b[0];
}

// ---------------------------------------------------------------------------

extern "C" void kernel_launch(void* const* d_in, const int* in_sizes, int n_in,
                              void* d_out, int out_size, void* d_ws, size_t ws_size,
                              hipStream_t stream) {
    const float* x     = (const float*)d_in[0];
    const int*   ei    = (const int*)d_in[1];
    const int*   batch = (const int*)d_in[2];
    const float* c1W1  = (const float*)d_in[3];
    const float* c1b1  = (const float*)d_in[4];
    const float* c1W2  = (const float*)d_in[5];
    const float* c1b2  = (const float*)d_in[6];
    const float* c1g   = (const float*)d_in[7];
    const float* c1be  = (const float*)d_in[8];
    const float* c1m   = (const float*)d_in[9];
    const float* c1v   = (const float*)d_in[10];
    const float* csW1  = (const float*)d_in[11];
    const float* csb1  = (const float*)d_in[12];
    const float* csW2  = (const float*)d_in[13];
    const float* csb2  = (const float*)d_in[14];
    const float* csg   = (const float*)d_in[15];
    const float* csbe  = (const float*)d_in[16];
    const float* csm   = (const float*)d_in[17];
    const float* csv   = (const float*)d_in[18];
    const float* lin1W = (const float*)d_in[19];
    const float* lin1b = (const float*)d_in[20];
    const float* lin2W = (const float*)d_in[21];
    const float* lin2b = (const float*)d_in[22];

    const int N = in_sizes[0] / 2;
    const int E = in_sizes[1] / 2;
    const int G = out_size;
    const int NL = in_sizes[11] / (128 * 128);  // 4
    const int nb = (N + 127) >> 7;              // buckets of 128 nodes

    char* ws = (char*)d_ws;
    size_t HS = (size_t)N * 128 * sizeof(unsigned short);      // bf16 feature plane
    unsigned short* h   = (unsigned short*)(ws);
    unsigned short* sum = (unsigned short*)(ws + HS);
    unsigned short* tmp = (unsigned short*)(ws + 2 * HS);
    char* p = ws + 3 * HS;
    float* sum2 = (float*)p;                 p += (((size_t)N * 2 * 4 + 15) / 16) * 16;
    unsigned short* Wp = (unsigned short*)p; p += ((9 * 16384 * 2 + 15) / 16) * 16;
    int* rowptr = (int*)p;                   p += (((size_t)(N + 1) * 4 + 15) / 16) * 16;
    int* col = (int*)p;                      p += (((size_t)E * 4 + 15) / 16) * 16;
    unsigned* staging = (unsigned*)p;        p += (((size_t)E * 4 + 15) / 16) * 16;
    int* bcnt = (int*)p;                     p += 512 * 4;
    int* boff = (int*)p;                     p += 513 * 4;
    int* bcur = (int*)p;                     p += 512 * 4;
    float* pooled = (float*)p;               p += (size_t)G * 128 * 4;

    const int* srcI = ei;
    const int* dstI = ei + E;

    const int NB = (N + 255) / 256;
    const int ET = (E + 4095) / 4096;

    // CSR build (bucketed, no scattered global writes)
    (void)hipMemsetAsync(bcnt, 0, 512 * 4, stream);
    (void)hipMemsetAsync(pooled, 0, (size_t)G * 128 * 4, stream);
    bucket_hist<<<ET, 256, 0, stream>>>(dstI, bcnt, E, nb);
    scan_buckets<<<1, 512, 0, stream>>>(bcnt, boff, bcur, rowptr, nb, N);
    bucket_scatter<<<ET, 256, 0, stream>>>(srcI, dstI, bcur, staging, E, nb);
    bucket_build<<<nb, 256, 0, stream>>>(staging, boff, rowptr, col, N);

    // weight packing
    pack_W_all<<<(1 + 2 * NL) * 64, 256, 0, stream>>>(c1W2, csW1, csW2, Wp, NL);

    const int GEMMB = (N + 31) / 32;     // 1-wave blocks, 32 rows each
    const int AGGB = ((N + 3) / 4 + 3) / 4;

    // layer 1 (input dim 2)
    agg2<<<NB, 256, 0, stream>>>(x, rowptr, col, sum2, N);
    mlp1a<<<(N * 128 + 255) / 256, 256, 0, stream>>>(sum2, c1W1, c1b1, tmp, N);
    gemm_one<<<GEMMB, 64, 0, stream>>>(tmp, Wp, c1b2, c1g, c1be, c1m, c1v, h, N);

    // layers 2..5
    for (int i = 0; i < NL; ++i) {
        aggH_bf16<<<AGGB, 256, 0, stream>>>((const uint4*)h, rowptr, col, (uint4*)sum, N);
        gin_mlp<<<GEMMB, 64, 0, stream>>>(sum,
                                          Wp + (size_t)(1 + i) * 16384, csb1 + i * 128,
                                          Wp + (size_t)(1 + NL + i) * 16384, csb2 + i * 128,
                                          csg + i * 128, csbe + i * 128, csm + i * 128,
                                          csv + i * 128, h, N);
    }

    // pooling + head
    pool_partial<<<(N + 31) / 32, 128, 0, stream>>>(h, batch, pooled, N);
    head<<<G, 128, 0, stream>>>(pooled, lin1W, lin1b, lin2W, lin2b, (float*)d_out);
}